// Round 5
// baseline (192.347 us; speedup 1.0000x reference)
//
#include <hip/hip_runtime.h>

typedef unsigned short u16;
typedef unsigned long long u64;

// ---------------- problem constants ----------------
constexpr int cB = 4, cT = 40, cR = 2000, cA = 36864;
constexpr int cH = 64, cW = 64, cC = 256, cPP = 7;
constexpr int cNCLS = 21, cNPOS = 64, cNNEG = 192, cDH = 1024;
constexpr int cD = cPP * cPP * cC;          // 12544
constexpr int cBA = cB * cA;                // 147456
constexpr int cBR = cB * cR;                // 8000
constexpr int NW64 = cBA / 64;              // 2304 mask words
constexpr int SPLITS = 14;                  // k-splits for gemm1
constexpr int KCH = cD / SPLITS;            // 896 = 14*64
constexpr int BK = 64;                      // k per iteration
constexpr int NITER = KCH / BK;             // 14
constexpr unsigned POSKEY = 0x007FFFFFu;    // f2key(-inf): marks iou>0.5

// ---------------- ws layout (bytes); no aliasing ----------------
constexpr size_t O_TIDX  = 0;                         // cBA int      -> 589824
constexpr size_t O_MASKW = 589824;                    // 2304 u64     -> 608256
constexpr size_t O_KEYS  = 608256;                    // 8000 u32     -> 640256
constexpr size_t O_RIDXG = 640256;                    // 8000 int     -> 672256
constexpr size_t O_SEL   = 672256;                    // 256 int
constexpr size_t O_CLS   = 673280;                    // 256 int
constexpr size_t O_ROIS  = 674304;                    // 256*4 f32
constexpr size_t O_TGT   = 678400;                    // 64*4 f32
constexpr size_t O_FMT   = 1048576;                   // B*HW*C bf16 = 8388608
constexpr size_t O_FEAT  = O_FMT + 8388608;           // 256*12544 bf16 = 6422528
constexpr size_t O_CPART = O_FEAT + 6422528;          // 14*256*1024 f32 = 14680064
constexpr size_t O_WT    = O_CPART + 14680064;        // 1024*12544 bf16 = 25690112

// ---------------- helpers ----------------
__device__ __forceinline__ float b2f(u16 u) {
  return __uint_as_float(((unsigned)u) << 16);
}
__device__ __forceinline__ u16 f2b(float f) {  // f32 -> bf16 bits (RNE)
  unsigned x = __float_as_uint(f);
  unsigned r = x + 0x7FFFu + ((x >> 16) & 1u);
  return (u16)(r >> 16);
}
__device__ __forceinline__ unsigned f2key(float f) {  // monotonic f32->u32
  unsigned b = __float_as_uint(f);
  return b ^ ((b & 0x80000000u) ? 0xFFFFFFFFu : 0x80000000u);
}

typedef __attribute__((ext_vector_type(8))) short short8;
typedef __attribute__((ext_vector_type(4))) float f32x4;

// ================= K1: fused RPN IoU + RCNN IoU + transposes ===============
// blocks 0..575: RPN; 576..607: RCNN; 608..1631: fm (B,C,HW) f32 -> (B,HW,C) bf16
// blocks 1632..4767: W1 (12544x1024 f32) -> Wt (1024x12544 bf16) transpose+convert
__global__ __launch_bounds__(256) void k_front(
    const float* __restrict__ bboxes, const float* __restrict__ anchors,
    const float* __restrict__ nms_reg, const float* __restrict__ fm,
    const float* __restrict__ W1,
    int* __restrict__ tidx, u64* __restrict__ maskw,
    unsigned* __restrict__ keys, int* __restrict__ ridxg,
    u16* __restrict__ fmt, u16* __restrict__ wt) {
  __shared__ float sfm[64 * 65];
  int bid = blockIdx.x;
  if (bid < 576) {
    float* sb = sfm;
    int b = bid / 144;
    if (threadIdx.x < cT * 4) sb[threadIdx.x] = bboxes[b * cT * 4 + threadIdx.x];
    __syncthreads();
    int i = bid * 256 + threadIdx.x;
    int a = i - b * cA;
    float4 av = ((const float4*)anchors)[a];
    float at = av.x, al = av.y, ab = av.z, ar = av.w;
    float area_a = (ab - at) * (ar - al);
    float best = -1.0f; int bi = 0;
    for (int t = 0; t < cT; ++t) {
      float bt = sb[t * 4], bl = sb[t * 4 + 1], bbv = sb[t * 4 + 2], brv = sb[t * 4 + 3];
      float ih = fmaxf(fminf(bbv, ab) - fmaxf(bt, at), 0.0f);
      float iw = fmaxf(fminf(brv, ar) - fmaxf(bl, al), 0.0f);
      float inter = ih * iw;
      float a1 = (bbv - bt) * (brv - bl);
      float iou = inter / (a1 + area_a - inter);
      if (iou > best) { best = iou; bi = t; }
    }
    tidx[i] = bi;
    u64 bal = __ballot(best > 0.5f);
    if ((threadIdx.x & 63) == 0) maskw[i >> 6] = bal;
  } else if (bid < 608) {
    float* sb = sfm;
    for (int j = threadIdx.x; j < cB * cT * 4; j += 256) sb[j] = bboxes[j];
    __syncthreads();
    int i = (bid - 576) * 256 + threadIdx.x;
    if (i >= cBR) return;
    int b = i / cR;
    float4 nv = ((const float4*)nms_reg)[i];
    float nt = nv.x, nl = nv.y, nb = nv.z, nr = nv.w;
    float area_n = (nb - nt) * (nr - nl);
    float best = -1.0f; int bi = 0;
    for (int t = 0; t < cT; ++t) {
      const float* bx = &sb[(b * cT + t) * 4];
      float ih = fmaxf(fminf(bx[2], nb) - fmaxf(bx[0], nt), 0.0f);
      float iw = fmaxf(fminf(bx[3], nr) - fmaxf(bx[1], nl), 0.0f);
      float inter = ih * iw;
      float a1 = (bx[2] - bx[0]) * (bx[3] - bx[1]);
      float iou = inter / (a1 + area_n - inter);
      if (iou > best) { best = iou; bi = t; }
    }
    keys[i] = (best <= 0.5f) ? f2key(best) : POSKEY;
    ridxg[i] = bi;
  } else if (bid < 1632) {
    int f = bid - 608;
    int b = f >> 8;
    int c0 = ((f >> 6) & 3) * 64;
    int p0 = (f & 63) * 64;
    int t = threadIdx.x;
    int pL = (t & 15) * 4, cL = t >> 4;
    #pragma unroll
    for (int i = 0; i < 4; ++i) {
      int c = cL + i * 16;
      float4 v = *(const float4*)&fm[((size_t)b * cC + c0 + c) * (cH * cW) + p0 + pL];
      sfm[c * 65 + pL] = v.x; sfm[c * 65 + pL + 1] = v.y;
      sfm[c * 65 + pL + 2] = v.z; sfm[c * 65 + pL + 3] = v.w;
    }
    __syncthreads();
    int pW = t >> 2, cg = (t & 3) * 16;
    unsigned pk[8];
    #pragma unroll
    for (int j = 0; j < 8; ++j) {
      unsigned lo = f2b(sfm[(cg + 2 * j) * 65 + pW]);
      unsigned hi = f2b(sfm[(cg + 2 * j + 1) * 65 + pW]);
      pk[j] = lo | (hi << 16);
    }
    u16* dst = &fmt[((size_t)b * (cH * cW) + p0 + pW) * cC + c0 + cg];
    *(uint4*)dst = *(uint4*)&pk[0];
    *(uint4*)(dst + 8) = *(uint4*)&pk[4];
  } else {
    // W1 transpose+convert: tile (k0..k0+63) x (n0..n0+63)
    int f = bid - 1632;               // 0..3135
    int kt = f % 196, nt = f / 196;   // 196 k-tiles, 16 n-tiles
    int k0 = kt * 64, n0 = nt * 64;
    int t = threadIdx.x;
    int n4 = (t & 15) * 4, kL = t >> 4;
    #pragma unroll
    for (int i = 0; i < 4; ++i) {
      int k = kL + i * 16;
      float4 v = *(const float4*)&W1[(size_t)(k0 + k) * cDH + n0 + n4];
      sfm[k * 65 + n4] = v.x; sfm[k * 65 + n4 + 1] = v.y;
      sfm[k * 65 + n4 + 2] = v.z; sfm[k * 65 + n4 + 3] = v.w;
    }
    __syncthreads();
    int n = t >> 2, kc = (t & 3) * 16;
    unsigned pk[8];
    #pragma unroll
    for (int j = 0; j < 8; ++j) {
      unsigned lo = f2b(sfm[(kc + 2 * j) * 65 + n]);
      unsigned hi = f2b(sfm[(kc + 2 * j + 1) * 65 + n]);
      pk[j] = lo | (hi << 16);
    }
    u16* dst = &wt[(size_t)(n0 + n) * cD + k0 + kc];
    *(uint4*)dst = *(uint4*)&pk[0];
    *(uint4*)(dst + 8) = *(uint4*)&pk[4];
  }
}

// ================= K2: fused selection (block 0: RPN, block 1: RCNN) ========
__global__ __launch_bounds__(1024) void k_select(
    const u64* __restrict__ maskw, const int* __restrict__ tidx,
    const float* __restrict__ rpn_cls, const float* __restrict__ rpn_reg,
    const float* __restrict__ bboxes, const float* __restrict__ anchors,
    const unsigned* __restrict__ keysg, const int* __restrict__ ridxg,
    const float* __restrict__ nms_reg, const int* __restrict__ classes,
    int* __restrict__ sel, int* __restrict__ cls_s,
    float* __restrict__ rois, float* __restrict__ tgt,
    float* __restrict__ out) {
  __shared__ __align__(16) char smem[50688];
  __shared__ float s_scalF[2];
  __shared__ int s_scalI[3];
  int tid = threadIdx.x, lane = tid & 63, w = tid >> 6;
  u64 lmask = (1ULL << lane) - 1ULL;

  if (blockIdx.x == 0) {
    if (tid < 4) out[2 + tid] = 0.0f;   // zero accumulators for k_heads
    u64* s_w   = (u64*)smem;
    int* s_pre = (int*)(smem + 18432);
    int* s_cw  = (int*)(smem + 19008);
    int* s_pos = (int*)(smem + 19584);
    int* s_neg = (int*)(smem + 20096);
    for (int k = tid; k < NW64; k += 1024) s_w[k] = maskw[k];
    if (tid < 128) s_pos[tid] = 0;
    if (tid < 252) s_neg[tid] = 0;
    if (tid == 0) { s_scalF[0] = 0.0f; s_scalF[1] = 0.0f; }
    __syncthreads();
    if (tid < 144) {
      int c = 0;
      #pragma unroll
      for (int k2 = 0; k2 < 16; ++k2) c += __popcll(s_w[tid * 16 + k2]);
      s_cw[tid] = c;
    }
    __syncthreads();
    if (tid == 0) {
      int run = 0;
      for (int ch = 0; ch < 144; ++ch) { s_pre[ch] = run; run += s_cw[ch]; }
    }
    __syncthreads();
    for (int ch = w; ch < 144; ch += 16) {
      int pbase = s_pre[ch];
      int nbase = ch * 1024 - pbase;
      if (pbase >= 128 && nbase >= 252) continue;
      int pc = 0;
      #pragma unroll
      for (int s2 = 0; s2 < 16; ++s2) {
        u64 word = s_w[ch * 16 + s2];
        bool m = (word >> lane) & 1ULL;
        int prefP = __popcll(word & lmask);
        int idx = ch * 1024 + s2 * 64 + lane;
        if (m) {
          int g = pbase + pc + prefP;
          if (g < 128) s_pos[g] = idx;
        } else {
          int g = nbase + (s2 * 64 + lane) - (pc + prefP);
          if (g < 252) s_neg[g] = idx;
        }
        pc += __popcll(word);
      }
    }
    __syncthreads();
    if (tid < 380) {
      int flat; float lbl;
      if (tid < 128) { flat = s_pos[tid]; lbl = 1.0f; }
      else           { flat = s_neg[tid - 128]; lbl = 0.0f; }
      float l = rpn_cls[flat];
      float term = fmaxf(l, 0.0f) - l * lbl + log1pf(expf(-fabsf(l)));
      atomicAdd(&s_scalF[0], term);
    }
    if (tid < 512) {
      int j = tid >> 2, c = tid & 3;
      int flat = s_pos[j];
      int b = flat / cA, a = flat - b * cA;
      int t = tidx[flat];
      float p = rpn_reg[flat * 4 + c];
      float tg = bboxes[(b * cT + t) * 4 + c] - anchors[a * 4 + c];
      float d = fabsf(p - tg);
      float sl = (d < 1.0f) ? 0.5f * d * d : d - 0.5f;
      atomicAdd(&s_scalF[1], sl);
    }
    __syncthreads();
    if (tid == 0) {
      out[0] = s_scalF[0] / 380.0f;
      out[1] = s_scalF[1] / 512.0f / 4.0f;
    }
  } else {
    unsigned* s_key = (unsigned*)smem;
    int* s_hist = (int*)(smem + 32000);
    int* s_pc   = (int*)(smem + 48384);
    int* s_wsum = (int*)(smem + 48896);
    int* s_wsuf = (int*)(smem + 48960);
    int* s_posr = (int*)(smem + 49024);
    int* s_negr = (int*)(smem + 49280);

    for (int i = tid; i < cBR; i += 1024) s_key[i] = keysg[i];
    if (tid < 64) s_posr[tid] = 0;
    __syncthreads();

    {
      int myv = 0; int mypre[8];
      #pragma unroll
      for (int p = 0; p < 8; ++p) {
        int i = p * 1024 + tid;
        bool v = (i < cBR) && (s_key[i] == POSKEY);
        u64 bal = __ballot(v);
        if (lane == 0) s_pc[p * 16 + w] = __popcll(bal);
        mypre[p] = __popcll(bal & lmask);
        myv |= v ? (1 << p) : 0;
      }
      __syncthreads();
      if (tid == 0) {
        int run = 0;
        for (int k = 0; k < 128; ++k) { int t = s_pc[k]; s_pc[k] = run; run += t; }
      }
      __syncthreads();
      #pragma unroll
      for (int p = 0; p < 8; ++p) {
        if (myv & (1 << p)) {
          int g = s_pc[p * 16 + w] + mypre[p];
          if (g < 64) s_posr[g] = p * 1024 + tid;
        }
      }
    }

    unsigned thr = 0; int G = 0;
    int need = cNNEG;
    #pragma unroll
    for (int lvl = 0; lvl < 3; ++lvl) {
      __syncthreads();
      #pragma unroll
      for (int k = 0; k < 4; ++k) s_hist[tid * 4 + k] = 0;
      __syncthreads();
      #pragma unroll
      for (int p = 0; p < 8; ++p) {
        int i = p * 1024 + tid;
        if (i < cBR) {
          unsigned key = s_key[i];
          int bkt = -1;
          if (lvl == 0) bkt = key >> 20;
          else if (lvl == 1) { if ((key >> 20) == (thr >> 20)) bkt = (key >> 8) & 0xFFF; }
          else { if ((key >> 8) == (thr >> 8)) bkt = (key & 0xFF) << 4; }
          if (bkt >= 0) atomicAdd(&s_hist[bkt], 1);
        }
      }
      __syncthreads();
      int local0 = s_hist[tid * 4 + 0], local1 = s_hist[tid * 4 + 1];
      int local2 = s_hist[tid * 4 + 2], local3 = s_hist[tid * 4 + 3];
      int lsum = local0 + local1 + local2 + local3;
      int x = lsum;
      #pragma unroll
      for (int off = 1; off < 64; off <<= 1) {
        int t = __shfl_down(x, off, 64);
        if (lane + off < 64) x += t;
      }
      if (lane == 0) s_wsum[w] = x;
      __syncthreads();
      if (tid == 0) {
        int run = 0;
        for (int wi = 15; wi >= 0; --wi) { s_wsuf[wi] = run; run += s_wsum[wi]; }
      }
      __syncthreads();
      int above = s_wsuf[w] + (x - lsum);
      int run = above;
      int loc[4] = {local3, local2, local1, local0};
      #pragma unroll
      for (int j = 0; j < 4; ++j) {
        int S = run + loc[j];
        if (run < need && S >= need) { s_scalI[0] = tid * 4 + (3 - j); s_scalI[1] = run; }
        run = S;
      }
      __syncthreads();
      int bS = s_scalI[0], ov = s_scalI[1];
      if (lvl == 0) thr = ((unsigned)bS) << 20;
      else if (lvl == 1) thr |= ((unsigned)bS) << 8;
      else thr |= ((unsigned)bS) >> 4;
      G += ov;
      need -= ov;
    }

    if (tid == 0) s_scalI[2] = 0;
    __syncthreads();
    #pragma unroll
    for (int p = 0; p < 8; ++p) {
      int i = p * 1024 + tid;
      if (i < cBR && s_key[i] > thr) {
        int slot = atomicAdd(&s_scalI[2], 1);
        s_negr[slot] = i;
      }
    }
    {
      __syncthreads();
      int myv = 0; int mypre[8];
      #pragma unroll
      for (int p = 0; p < 8; ++p) {
        int i = p * 1024 + tid;
        bool v = (i < cBR) && (s_key[i] == thr);
        u64 bal = __ballot(v);
        if (lane == 0) s_pc[p * 16 + w] = __popcll(bal);
        mypre[p] = __popcll(bal & lmask);
        myv |= v ? (1 << p) : 0;
      }
      __syncthreads();
      if (tid == 0) {
        int run = 0;
        for (int k = 0; k < 128; ++k) { int t = s_pc[k]; s_pc[k] = run; run += t; }
      }
      __syncthreads();
      #pragma unroll
      for (int p = 0; p < 8; ++p) {
        if (myv & (1 << p)) {
          int g = s_pc[p * 16 + w] + mypre[p];
          if (g < need) s_negr[G + g] = p * 1024 + tid;
        }
      }
    }
    __syncthreads();

    if (tid < 256) {
      int flat = (tid < 64) ? s_posr[tid] : s_negr[tid - 64];
      sel[tid] = flat;
      int b = flat / cR;
      #pragma unroll
      for (int c = 0; c < 4; ++c) rois[tid * 4 + c] = nms_reg[flat * 4 + c];
      cls_s[tid] = (tid < 64) ? classes[b * cT + ridxg[flat]] : 0;
      if (tid < 64) {
        int mt = ridxg[flat];
        #pragma unroll
        for (int c = 0; c < 4; ++c) {
          float v = nms_reg[flat * 4 + c];
          float rr = ((c < 2) ? floorf(v * 16.0f) : ceilf(v * 16.0f)) / 16.0f;
          float mbv = bboxes[(b * cT + mt) * 4 + c];
          tgt[tid * 4 + c] = mbv - rr;
        }
      }
    }
  }
}

// ================= K3: ROI align (coalesced, one block per roi x bin-row) ===
__global__ void k_roi_pool(const u16* __restrict__ fmt, const float* __restrict__ rois,
                           const int* __restrict__ sel, u16* __restrict__ feat) {
  int j = blockIdx.x;
  int py = blockIdx.y;
  int c = threadIdx.x;
  int flat = sel[j];
  int n = flat / cR;
  float t = rois[j * 4 + 0], l = rois[j * 4 + 1];
  float bb = rois[j * 4 + 2], r = rois[j * 4 + 3];
  const u16* base = fmt + (size_t)n * (cH * cW) * cC;
  float gy = (py + 0.5f) / (float)cPP;
  float ys = fminf(fmaxf(t + gy * (bb - t), 0.0f), 63.0f);
  int y0 = (int)floorf(ys);
  int y1 = min(y0 + 1, 63);
  float wy = ys - (float)y0;
  #pragma unroll
  for (int px = 0; px < cPP; ++px) {
    float gx = (px + 0.5f) / (float)cPP;
    float xs = fminf(fmaxf(l + gx * (r - l), 0.0f), 63.0f);
    int x0 = (int)floorf(xs);
    int x1 = min(x0 + 1, 63);
    float wx = xs - (float)x0;
    float f00 = b2f(base[(y0 * cW + x0) * cC + c]);
    float f01 = b2f(base[(y0 * cW + x1) * cC + c]);
    float f10 = b2f(base[(y1 * cW + x0) * cC + c]);
    float f11 = b2f(base[(y1 * cW + x1) * cC + c]);
    float v = f00 * (1.0f - wy) * (1.0f - wx) + f01 * (1.0f - wy) * wx +
              f10 * wy * (1.0f - wx) + f11 * wy * wx;
    feat[((size_t)j * 49 + py * cPP + px) * cC + c] = f2b(v);
  }
}

// ================= K4: GEMM1 feat(256x12544 bf16) @ Wt(1024x12544 bf16)^T ===
// 1792 blocks (7/CU) XCD-grouped: the 4 m-blocks sharing a (n,ksp) Wt tile are
// consecutive on one XCD -> Wt mostly L2-hit; per-XCD A working set ~458 KB
// (L2-resident). All loads k-contiguous dwordx4 (the 4KB-strided W1 read was
// the 41us wall in rounds 0/1/3/4). A direct global->reg (no LDS; zero reuse).
// B: 1 dwordx4/thread/phase -> 4-deep reg ring -> swizzled Bs dbuf.
// Raw s_barrier + lgkm-only drain: B/A prefetches stay in flight across
// barriers (compiler emits precise counted vmcnt for the register deps).
__global__ __launch_bounds__(256) void k_gemm1(const u16* __restrict__ feat, const u16* __restrict__ Wt,
                                               float* __restrict__ Cpart) {
  __shared__ u16 Bs[2][32][64];      // 8 KB, 16B-chunk XOR swizzle both sides
  int tid = threadIdx.x;
  int bid = blockIdx.x;              // 0..1791
  int xcd = bid & 7, jj = bid >> 3;  // jj 0..223
  int gl = jj >> 2, m = jj & 3;      // gl 0..55
  int g = gl * 8 + xcd;              // 0..447 (bijective: 1792 % 8 == 0)
  int n0 = (g & 31) * 32;
  int ksp = g >> 5;                  // 0..13
  int kb0 = ksp * KCH;
  int m0 = m * 64;
  int lane = tid & 63, w = tid >> 6;
  int r = lane & 15, q = lane >> 4;
  int rb = r & 7;

  f32x4 acc0 = {}, acc1 = {};

  // --- B staging: 8 consecutive lanes load one Wt row's 128B (8 chunks) ---
  int bn = tid >> 3, bc = tid & 7;   // row 0..31, chunk 0..7
  int bcs = (bc ^ (bn & 7)) * 8;     // swizzled elem offset
  const u16* bp0 = &Wt[(size_t)(n0 + bn) * cD + kb0 + bc * 8];

  // --- B fragment read offsets (chunk c stored at c^(row&7)) ---
  int offK0 = (q ^ rb) * 8;          // orig chunk q     (ks=0)
  int offK1 = ((4 + q) ^ rb) * 8;    // orig chunk 4+q   (ks=1)

  // --- A: lane owns row m0 + w*16 + r, k chunks q*8 (ks0) / 32+q*8 (ks1) ---
  const u16* afp = &feat[(size_t)(m0 + w * 16 + r) * cD + kb0 + q * 8];

  uint4 BR[4];                       // 4-phase-deep B prefetch ring
  short8 A[2][2];                    // 2-phase-deep A ping-pong

#define LOADB(slot, ph) { BR[slot] = *(const uint4*)(bp0 + (ph) * BK); }
#define STOREB(buf, slot) { *(uint4*)&Bs[buf][bn][bcs] = BR[slot]; }
#define LOADA(set, ph) { const u16* _p = afp + (ph) * BK; \
    A[set][0] = *(const short8*)_p; \
    A[set][1] = *(const short8*)(_p + 32); }
#define COMPUTE(buf, set) { \
    short8 b00 = *(const short8*)&Bs[buf][r][offK0]; \
    short8 b10 = *(const short8*)&Bs[buf][16 + r][offK0]; \
    short8 b01 = *(const short8*)&Bs[buf][r][offK1]; \
    short8 b11 = *(const short8*)&Bs[buf][16 + r][offK1]; \
    acc0 = __builtin_amdgcn_mfma_f32_16x16x32_bf16(A[set][0], b00, acc0, 0, 0, 0); \
    acc1 = __builtin_amdgcn_mfma_f32_16x16x32_bf16(A[set][0], b10, acc1, 0, 0, 0); \
    acc0 = __builtin_amdgcn_mfma_f32_16x16x32_bf16(A[set][1], b01, acc0, 0, 0, 0); \
    acc1 = __builtin_amdgcn_mfma_f32_16x16x32_bf16(A[set][1], b11, acc1, 0, 0, 0); }
#define BARRIER() { \
    asm volatile("s_waitcnt lgkmcnt(0)" ::: "memory"); \
    __builtin_amdgcn_s_barrier(); \
    __builtin_amdgcn_sched_barrier(0); }

  // prologue: fill B ring (4 tiles), A ping-pong (2 tiles), stage B(0)
  LOADB(0, 0); LOADB(1, 1); LOADB(2, 2); LOADB(3, 3);
  LOADA(0, 0); LOADA(1, 1);
  STOREB(0, 0);
  BARRIER();

  #pragma unroll
  for (int p = 0; p < NITER; ++p) {
    if (p + 1 < NITER) STOREB((p + 1) & 1, (p + 1) & 3);  // counted-vmcnt wait (loaded 4 tiles ago)
    if (p + 4 < NITER) LOADB(p & 3, p + 4);
    __builtin_amdgcn_s_setprio(1);
    COMPUTE(p & 1, p & 1);
    __builtin_amdgcn_s_setprio(0);
    if (p + 2 < NITER) LOADA(p & 1, p + 2);
    BARRIER();
  }

#undef LOADB
#undef STOREB
#undef LOADA
#undef COMPUTE
#undef BARRIER

  float* Cp = Cpart + (size_t)ksp * 256 * cDH;
  #pragma unroll
  for (int rg = 0; rg < 4; ++rg) {
    int row = m0 + w * 16 + q * 4 + rg;
    Cp[(size_t)row * cDH + n0 + r] = acc0[rg];
    Cp[(size_t)row * cDH + n0 + 16 + r] = acc1[rg];
  }
}

// ================= K5: heads + final losses (one block per roi row) =========
__global__ __launch_bounds__(256) void k_heads(
    const float* __restrict__ Cpart, const float* __restrict__ b1,
    const float* __restrict__ Wr, const float* __restrict__ br,
    const float* __restrict__ Wc, const float* __restrict__ bc,
    const int* __restrict__ cls_s, const float* __restrict__ tgt,
    float* __restrict__ out) {
  __shared__ float sacc[25];
  int row = blockIdx.x, tid = threadIdx.x, lane = tid & 63;
  if (tid < 25) sacc[tid] = 0.0f;
  __syncthreads();
  int k0 = tid * 4;
  float4 h = *(const float4*)&b1[k0];
  #pragma unroll
  for (int s = 0; s < SPLITS; ++s) {
    float4 c = *(const float4*)&Cpart[(size_t)s * 256 * cDH + (size_t)row * cDH + k0];
    h.x += c.x; h.y += c.y; h.z += c.z; h.w += c.w;
  }
  float hv[4] = {fmaxf(h.x, 0.f), fmaxf(h.y, 0.f), fmaxf(h.z, 0.f), fmaxf(h.w, 0.f)};
  float part[25];
  #pragma unroll
  for (int c = 0; c < 25; ++c) part[c] = 0.0f;
  #pragma unroll
  for (int j = 0; j < 4; ++j) {
    float4 wr = *(const float4*)&Wr[(k0 + j) * 4];
    part[0] += hv[j] * wr.x; part[1] += hv[j] * wr.y;
    part[2] += hv[j] * wr.z; part[3] += hv[j] * wr.w;
    const float* wc = &Wc[(k0 + j) * 21];
    #pragma unroll
    for (int c = 0; c < 21; ++c) part[4 + c] += hv[j] * wc[c];
  }
  #pragma unroll
  for (int off = 32; off; off >>= 1) {
    #pragma unroll
    for (int c = 0; c < 25; ++c) part[c] += __shfl_down(part[c], off, 64);
  }
  if (lane == 0) {
    #pragma unroll
    for (int c = 0; c < 25; ++c) atomicAdd(&sacc[c], part[c]);
  }
  __syncthreads();
  if (tid == 0) {
    int cls = cls_s[row];
    float m = -INFINITY;
    float vals[21];
    #pragma unroll
    for (int c = 0; c < 21; ++c) { vals[c] = sacc[4 + c] + bc[c]; m = fmaxf(m, vals[c]); }
    float sum = 0.0f;
    #pragma unroll
    for (int c = 0; c < 21; ++c) sum += expf(vals[c] - m);
    float lse = m + logf(sum);
    atomicAdd(&out[2], (lse - vals[cls]) * (1.0f / 256.0f));
    if (row < 64) {
      int am2 = 0; float bv = vals[0];
      #pragma unroll
      for (int c = 1; c < 21; ++c) if (vals[c] > bv) { bv = vals[c]; am2 = c; }
      if (am2 == cls) atomicAdd(&out[4], 1.0f / 64.0f);
    }
  }
  if (tid == 1 && row < 64) {
    float sl = 0.0f, of = 0.0f;
    #pragma unroll
    for (int c = 0; c < 4; ++c) {
      float d = fabsf((sacc[c] + br[c]) - tgt[row * 4 + c]);
      sl += (d < 1.0f) ? 0.5f * d * d : d - 0.5f;
      of += d;
    }
    atomicAdd(&out[3], sl * (1.0f / 256.0f));
    atomicAdd(&out[5], of * (1.0f / 256.0f));
  }
}

// ================= launch =================
extern "C" void kernel_launch(void* const* d_in, const int* in_sizes, int n_in,
                              void* d_out, int out_size, void* d_ws, size_t ws_size,
                              hipStream_t stream) {
  const float* nms_reg = (const float*)d_in[0];
  const float* fm      = (const float*)d_in[2];
  const float* bboxes  = (const float*)d_in[3];
  const int*   classes = (const int*)d_in[4];
  const float* anchors = (const float*)d_in[5];
  const float* rpn_reg = (const float*)d_in[6];
  const float* rpn_cls = (const float*)d_in[7];
  const float* W1      = (const float*)d_in[8];
  const float* b1      = (const float*)d_in[9];
  const float* Wr      = (const float*)d_in[10];
  const float* br      = (const float*)d_in[11];
  const float* Wc      = (const float*)d_in[12];
  const float* bc      = (const float*)d_in[13];
  float* out = (float*)d_out;
  char* ws = (char*)d_ws;

  int*      tidx  = (int*)(ws + O_TIDX);
  u64*      maskw = (u64*)(ws + O_MASKW);
  unsigned* keys  = (unsigned*)(ws + O_KEYS);
  int*      ridxg = (int*)(ws + O_RIDXG);
  int*      sel   = (int*)(ws + O_SEL);
  int*      clss  = (int*)(ws + O_CLS);
  float*    rois  = (float*)(ws + O_ROIS);
  float*    tgt   = (float*)(ws + O_TGT);
  u16*      fmt   = (u16*)(ws + O_FMT);
  u16*      feat  = (u16*)(ws + O_FEAT);
  float*    Cpart = (float*)(ws + O_CPART);
  u16*      wt    = (u16*)(ws + O_WT);

  k_front<<<608 + 1024 + 3136, 256, 0, stream>>>(bboxes, anchors, nms_reg, fm, W1,
                                                 tidx, maskw, keys, ridxg, fmt, wt);
  k_select<<<2, 1024, 0, stream>>>(maskw, tidx, rpn_cls, rpn_reg, bboxes, anchors,
                                   keys, ridxg, nms_reg, classes, sel, clss, rois, tgt, out);
  k_roi_pool<<<dim3(256, cPP), 256, 0, stream>>>(fmt, rois, sel, feat);
  k_gemm1<<<1792, 256, 0, stream>>>(feat, wt, Cpart);
  k_heads<<<256, 256, 0, stream>>>(Cpart, b1, Wr, br, Wc, bc, clss, tgt, out);
}

// Round 6
// 184.144 us; speedup vs baseline: 1.0446x; 1.0446x over previous
//
#include <hip/hip_runtime.h>

typedef unsigned short u16;
typedef unsigned long long u64;

// ---------------- problem constants ----------------
constexpr int cB = 4, cT = 40, cR = 2000, cA = 36864;
constexpr int cH = 64, cW = 64, cC = 256, cPP = 7;
constexpr int cNCLS = 21, cNPOS = 64, cNNEG = 192, cDH = 1024;
constexpr int cD = cPP * cPP * cC;          // 12544
constexpr int cBA = cB * cA;                // 147456
constexpr int cBR = cB * cR;                // 8000
constexpr int NW64 = cBA / 64;              // 2304 mask words
constexpr int SPLITS = 14;                  // k-splits for gemm1
constexpr int KCH = cD / SPLITS;            // 896 = 14*64
constexpr int BK = 64;                      // k per iteration
constexpr int NITER = KCH / BK;             // 14
constexpr unsigned POSKEY = 0x007FFFFFu;    // f2key(-inf): marks iou>0.5

// ---------------- ws layout (bytes); no aliasing ----------------
constexpr size_t O_TIDX  = 0;                         // cBA int      -> 589824
constexpr size_t O_MASKW = 589824;                    // 2304 u64     -> 608256
constexpr size_t O_KEYS  = 608256;                    // 8000 u32     -> 640256
constexpr size_t O_RIDXG = 640256;                    // 8000 int     -> 672256
constexpr size_t O_SEL   = 672256;                    // 256 int
constexpr size_t O_CLS   = 673280;                    // 256 int
constexpr size_t O_ROIS  = 674304;                    // 256*4 f32
constexpr size_t O_TGT   = 678400;                    // 64*4 f32
constexpr size_t O_FMT   = 1048576;                   // B*HW*C bf16 = 8388608
constexpr size_t O_FEAT  = O_FMT + 8388608;           // 256*12544 bf16 = 6422528
constexpr size_t O_CPART = O_FEAT + 6422528;          // 14*256*1024 f32 = 14680064
constexpr size_t O_WT    = O_CPART + 14680064;        // 1024*12544 bf16 = 25690112

// ---------------- helpers ----------------
__device__ __forceinline__ float b2f(u16 u) {
  return __uint_as_float(((unsigned)u) << 16);
}
__device__ __forceinline__ u16 f2b(float f) {  // f32 -> bf16 bits (RNE)
  unsigned x = __float_as_uint(f);
  unsigned r = x + 0x7FFFu + ((x >> 16) & 1u);
  return (u16)(r >> 16);
}
__device__ __forceinline__ unsigned f2key(float f) {  // monotonic f32->u32
  unsigned b = __float_as_uint(f);
  return b ^ ((b & 0x80000000u) ? 0xFFFFFFFFu : 0x80000000u);
}

typedef __attribute__((ext_vector_type(8))) short short8;
typedef __attribute__((ext_vector_type(4))) float f32x4;

// ================= K1: fused RPN IoU + RCNN IoU + transposes ===============
// blocks 0..575: RPN; 576..607: RCNN; 608..1631: fm (B,C,HW) f32 -> (B,HW,C) bf16
// blocks 1632..4767: W1 (12544x1024 f32) -> Wt (1024x12544 bf16) transpose+convert
__global__ __launch_bounds__(256) void k_front(
    const float* __restrict__ bboxes, const float* __restrict__ anchors,
    const float* __restrict__ nms_reg, const float* __restrict__ fm,
    const float* __restrict__ W1,
    int* __restrict__ tidx, u64* __restrict__ maskw,
    unsigned* __restrict__ keys, int* __restrict__ ridxg,
    u16* __restrict__ fmt, u16* __restrict__ wt) {
  __shared__ float sfm[64 * 65];
  int bid = blockIdx.x;
  if (bid < 576) {
    float* sb = sfm;
    int b = bid / 144;
    if (threadIdx.x < cT * 4) sb[threadIdx.x] = bboxes[b * cT * 4 + threadIdx.x];
    __syncthreads();
    int i = bid * 256 + threadIdx.x;
    int a = i - b * cA;
    float4 av = ((const float4*)anchors)[a];
    float at = av.x, al = av.y, ab = av.z, ar = av.w;
    float area_a = (ab - at) * (ar - al);
    float best = -1.0f; int bi = 0;
    for (int t = 0; t < cT; ++t) {
      float bt = sb[t * 4], bl = sb[t * 4 + 1], bbv = sb[t * 4 + 2], brv = sb[t * 4 + 3];
      float ih = fmaxf(fminf(bbv, ab) - fmaxf(bt, at), 0.0f);
      float iw = fmaxf(fminf(brv, ar) - fmaxf(bl, al), 0.0f);
      float inter = ih * iw;
      float a1 = (bbv - bt) * (brv - bl);
      float iou = inter / (a1 + area_a - inter);
      if (iou > best) { best = iou; bi = t; }
    }
    tidx[i] = bi;
    u64 bal = __ballot(best > 0.5f);
    if ((threadIdx.x & 63) == 0) maskw[i >> 6] = bal;
  } else if (bid < 608) {
    float* sb = sfm;
    for (int j = threadIdx.x; j < cB * cT * 4; j += 256) sb[j] = bboxes[j];
    __syncthreads();
    int i = (bid - 576) * 256 + threadIdx.x;
    if (i >= cBR) return;
    int b = i / cR;
    float4 nv = ((const float4*)nms_reg)[i];
    float nt = nv.x, nl = nv.y, nb = nv.z, nr = nv.w;
    float area_n = (nb - nt) * (nr - nl);
    float best = -1.0f; int bi = 0;
    for (int t = 0; t < cT; ++t) {
      const float* bx = &sb[(b * cT + t) * 4];
      float ih = fmaxf(fminf(bx[2], nb) - fmaxf(bx[0], nt), 0.0f);
      float iw = fmaxf(fminf(bx[3], nr) - fmaxf(bx[1], nl), 0.0f);
      float inter = ih * iw;
      float a1 = (bx[2] - bx[0]) * (bx[3] - bx[1]);
      float iou = inter / (a1 + area_n - inter);
      if (iou > best) { best = iou; bi = t; }
    }
    keys[i] = (best <= 0.5f) ? f2key(best) : POSKEY;
    ridxg[i] = bi;
  } else if (bid < 1632) {
    int f = bid - 608;
    int b = f >> 8;
    int c0 = ((f >> 6) & 3) * 64;
    int p0 = (f & 63) * 64;
    int t = threadIdx.x;
    int pL = (t & 15) * 4, cL = t >> 4;
    #pragma unroll
    for (int i = 0; i < 4; ++i) {
      int c = cL + i * 16;
      float4 v = *(const float4*)&fm[((size_t)b * cC + c0 + c) * (cH * cW) + p0 + pL];
      sfm[c * 65 + pL] = v.x; sfm[c * 65 + pL + 1] = v.y;
      sfm[c * 65 + pL + 2] = v.z; sfm[c * 65 + pL + 3] = v.w;
    }
    __syncthreads();
    int pW = t >> 2, cg = (t & 3) * 16;
    unsigned pk[8];
    #pragma unroll
    for (int j = 0; j < 8; ++j) {
      unsigned lo = f2b(sfm[(cg + 2 * j) * 65 + pW]);
      unsigned hi = f2b(sfm[(cg + 2 * j + 1) * 65 + pW]);
      pk[j] = lo | (hi << 16);
    }
    u16* dst = &fmt[((size_t)b * (cH * cW) + p0 + pW) * cC + c0 + cg];
    *(uint4*)dst = *(uint4*)&pk[0];
    *(uint4*)(dst + 8) = *(uint4*)&pk[4];
  } else {
    // W1 transpose+convert: tile (k0..k0+63) x (n0..n0+63)
    int f = bid - 1632;               // 0..3135
    int kt = f % 196, nt = f / 196;   // 196 k-tiles, 16 n-tiles
    int k0 = kt * 64, n0 = nt * 64;
    int t = threadIdx.x;
    int n4 = (t & 15) * 4, kL = t >> 4;
    #pragma unroll
    for (int i = 0; i < 4; ++i) {
      int k = kL + i * 16;
      float4 v = *(const float4*)&W1[(size_t)(k0 + k) * cDH + n0 + n4];
      sfm[k * 65 + n4] = v.x; sfm[k * 65 + n4 + 1] = v.y;
      sfm[k * 65 + n4 + 2] = v.z; sfm[k * 65 + n4 + 3] = v.w;
    }
    __syncthreads();
    int n = t >> 2, kc = (t & 3) * 16;
    unsigned pk[8];
    #pragma unroll
    for (int j = 0; j < 8; ++j) {
      unsigned lo = f2b(sfm[(kc + 2 * j) * 65 + n]);
      unsigned hi = f2b(sfm[(kc + 2 * j + 1) * 65 + n]);
      pk[j] = lo | (hi << 16);
    }
    u16* dst = &wt[(size_t)(n0 + n) * cD + k0 + kc];
    *(uint4*)dst = *(uint4*)&pk[0];
    *(uint4*)(dst + 8) = *(uint4*)&pk[4];
  }
}

// ================= K2: fused selection (block 0: RPN, block 1: RCNN) ========
__global__ __launch_bounds__(1024) void k_select(
    const u64* __restrict__ maskw, const int* __restrict__ tidx,
    const float* __restrict__ rpn_cls, const float* __restrict__ rpn_reg,
    const float* __restrict__ bboxes, const float* __restrict__ anchors,
    const unsigned* __restrict__ keysg, const int* __restrict__ ridxg,
    const float* __restrict__ nms_reg, const int* __restrict__ classes,
    int* __restrict__ sel, int* __restrict__ cls_s,
    float* __restrict__ rois, float* __restrict__ tgt,
    float* __restrict__ out) {
  __shared__ __align__(16) char smem[50688];
  __shared__ float s_scalF[2];
  __shared__ int s_scalI[3];
  int tid = threadIdx.x, lane = tid & 63, w = tid >> 6;
  u64 lmask = (1ULL << lane) - 1ULL;

  if (blockIdx.x == 0) {
    if (tid < 4) out[2 + tid] = 0.0f;   // zero accumulators for k_heads
    u64* s_w   = (u64*)smem;
    int* s_pre = (int*)(smem + 18432);
    int* s_cw  = (int*)(smem + 19008);
    int* s_pos = (int*)(smem + 19584);
    int* s_neg = (int*)(smem + 20096);
    for (int k = tid; k < NW64; k += 1024) s_w[k] = maskw[k];
    if (tid < 128) s_pos[tid] = 0;
    if (tid < 252) s_neg[tid] = 0;
    if (tid == 0) { s_scalF[0] = 0.0f; s_scalF[1] = 0.0f; }
    __syncthreads();
    if (tid < 144) {
      int c = 0;
      #pragma unroll
      for (int k2 = 0; k2 < 16; ++k2) c += __popcll(s_w[tid * 16 + k2]);
      s_cw[tid] = c;
    }
    __syncthreads();
    if (tid == 0) {
      int run = 0;
      for (int ch = 0; ch < 144; ++ch) { s_pre[ch] = run; run += s_cw[ch]; }
    }
    __syncthreads();
    for (int ch = w; ch < 144; ch += 16) {
      int pbase = s_pre[ch];
      int nbase = ch * 1024 - pbase;
      if (pbase >= 128 && nbase >= 252) continue;
      int pc = 0;
      #pragma unroll
      for (int s2 = 0; s2 < 16; ++s2) {
        u64 word = s_w[ch * 16 + s2];
        bool m = (word >> lane) & 1ULL;
        int prefP = __popcll(word & lmask);
        int idx = ch * 1024 + s2 * 64 + lane;
        if (m) {
          int g = pbase + pc + prefP;
          if (g < 128) s_pos[g] = idx;
        } else {
          int g = nbase + (s2 * 64 + lane) - (pc + prefP);
          if (g < 252) s_neg[g] = idx;
        }
        pc += __popcll(word);
      }
    }
    __syncthreads();
    if (tid < 380) {
      int flat; float lbl;
      if (tid < 128) { flat = s_pos[tid]; lbl = 1.0f; }
      else           { flat = s_neg[tid - 128]; lbl = 0.0f; }
      float l = rpn_cls[flat];
      float term = fmaxf(l, 0.0f) - l * lbl + log1pf(expf(-fabsf(l)));
      atomicAdd(&s_scalF[0], term);
    }
    if (tid < 512) {
      int j = tid >> 2, c = tid & 3;
      int flat = s_pos[j];
      int b = flat / cA, a = flat - b * cA;
      int t = tidx[flat];
      float p = rpn_reg[flat * 4 + c];
      float tg = bboxes[(b * cT + t) * 4 + c] - anchors[a * 4 + c];
      float d = fabsf(p - tg);
      float sl = (d < 1.0f) ? 0.5f * d * d : d - 0.5f;
      atomicAdd(&s_scalF[1], sl);
    }
    __syncthreads();
    if (tid == 0) {
      out[0] = s_scalF[0] / 380.0f;
      out[1] = s_scalF[1] / 512.0f / 4.0f;
    }
  } else {
    unsigned* s_key = (unsigned*)smem;
    int* s_hist = (int*)(smem + 32000);
    int* s_pc   = (int*)(smem + 48384);
    int* s_wsum = (int*)(smem + 48896);
    int* s_wsuf = (int*)(smem + 48960);
    int* s_posr = (int*)(smem + 49024);
    int* s_negr = (int*)(smem + 49280);

    for (int i = tid; i < cBR; i += 1024) s_key[i] = keysg[i];
    if (tid < 64) s_posr[tid] = 0;
    __syncthreads();

    {
      int myv = 0; int mypre[8];
      #pragma unroll
      for (int p = 0; p < 8; ++p) {
        int i = p * 1024 + tid;
        bool v = (i < cBR) && (s_key[i] == POSKEY);
        u64 bal = __ballot(v);
        if (lane == 0) s_pc[p * 16 + w] = __popcll(bal);
        mypre[p] = __popcll(bal & lmask);
        myv |= v ? (1 << p) : 0;
      }
      __syncthreads();
      if (tid == 0) {
        int run = 0;
        for (int k = 0; k < 128; ++k) { int t = s_pc[k]; s_pc[k] = run; run += t; }
      }
      __syncthreads();
      #pragma unroll
      for (int p = 0; p < 8; ++p) {
        if (myv & (1 << p)) {
          int g = s_pc[p * 16 + w] + mypre[p];
          if (g < 64) s_posr[g] = p * 1024 + tid;
        }
      }
    }

    unsigned thr = 0; int G = 0;
    int need = cNNEG;
    #pragma unroll
    for (int lvl = 0; lvl < 3; ++lvl) {
      __syncthreads();
      #pragma unroll
      for (int k = 0; k < 4; ++k) s_hist[tid * 4 + k] = 0;
      __syncthreads();
      #pragma unroll
      for (int p = 0; p < 8; ++p) {
        int i = p * 1024 + tid;
        if (i < cBR) {
          unsigned key = s_key[i];
          int bkt = -1;
          if (lvl == 0) bkt = key >> 20;
          else if (lvl == 1) { if ((key >> 20) == (thr >> 20)) bkt = (key >> 8) & 0xFFF; }
          else { if ((key >> 8) == (thr >> 8)) bkt = (key & 0xFF) << 4; }
          if (bkt >= 0) atomicAdd(&s_hist[bkt], 1);
        }
      }
      __syncthreads();
      int local0 = s_hist[tid * 4 + 0], local1 = s_hist[tid * 4 + 1];
      int local2 = s_hist[tid * 4 + 2], local3 = s_hist[tid * 4 + 3];
      int lsum = local0 + local1 + local2 + local3;
      int x = lsum;
      #pragma unroll
      for (int off = 1; off < 64; off <<= 1) {
        int t = __shfl_down(x, off, 64);
        if (lane + off < 64) x += t;
      }
      if (lane == 0) s_wsum[w] = x;
      __syncthreads();
      if (tid == 0) {
        int run = 0;
        for (int wi = 15; wi >= 0; --wi) { s_wsuf[wi] = run; run += s_wsum[wi]; }
      }
      __syncthreads();
      int above = s_wsuf[w] + (x - lsum);
      int run = above;
      int loc[4] = {local3, local2, local1, local0};
      #pragma unroll
      for (int j = 0; j < 4; ++j) {
        int S = run + loc[j];
        if (run < need && S >= need) { s_scalI[0] = tid * 4 + (3 - j); s_scalI[1] = run; }
        run = S;
      }
      __syncthreads();
      int bS = s_scalI[0], ov = s_scalI[1];
      if (lvl == 0) thr = ((unsigned)bS) << 20;
      else if (lvl == 1) thr |= ((unsigned)bS) << 8;
      else thr |= ((unsigned)bS) >> 4;
      G += ov;
      need -= ov;
    }

    if (tid == 0) s_scalI[2] = 0;
    __syncthreads();
    #pragma unroll
    for (int p = 0; p < 8; ++p) {
      int i = p * 1024 + tid;
      if (i < cBR && s_key[i] > thr) {
        int slot = atomicAdd(&s_scalI[2], 1);
        s_negr[slot] = i;
      }
    }
    {
      __syncthreads();
      int myv = 0; int mypre[8];
      #pragma unroll
      for (int p = 0; p < 8; ++p) {
        int i = p * 1024 + tid;
        bool v = (i < cBR) && (s_key[i] == thr);
        u64 bal = __ballot(v);
        if (lane == 0) s_pc[p * 16 + w] = __popcll(bal);
        mypre[p] = __popcll(bal & lmask);
        myv |= v ? (1 << p) : 0;
      }
      __syncthreads();
      if (tid == 0) {
        int run = 0;
        for (int k = 0; k < 128; ++k) { int t = s_pc[k]; s_pc[k] = run; run += t; }
      }
      __syncthreads();
      #pragma unroll
      for (int p = 0; p < 8; ++p) {
        if (myv & (1 << p)) {
          int g = s_pc[p * 16 + w] + mypre[p];
          if (g < need) s_negr[G + g] = p * 1024 + tid;
        }
      }
    }
    __syncthreads();

    if (tid < 256) {
      int flat = (tid < 64) ? s_posr[tid] : s_negr[tid - 64];
      sel[tid] = flat;
      int b = flat / cR;
      #pragma unroll
      for (int c = 0; c < 4; ++c) rois[tid * 4 + c] = nms_reg[flat * 4 + c];
      cls_s[tid] = (tid < 64) ? classes[b * cT + ridxg[flat]] : 0;
      if (tid < 64) {
        int mt = ridxg[flat];
        #pragma unroll
        for (int c = 0; c < 4; ++c) {
          float v = nms_reg[flat * 4 + c];
          float rr = ((c < 2) ? floorf(v * 16.0f) : ceilf(v * 16.0f)) / 16.0f;
          float mbv = bboxes[(b * cT + mt) * 4 + c];
          tgt[tid * 4 + c] = mbv - rr;
        }
      }
    }
  }
}

// ================= K3: ROI align (coalesced, one block per roi x bin-row) ===
__global__ void k_roi_pool(const u16* __restrict__ fmt, const float* __restrict__ rois,
                           const int* __restrict__ sel, u16* __restrict__ feat) {
  int j = blockIdx.x;
  int py = blockIdx.y;
  int c = threadIdx.x;
  int flat = sel[j];
  int n = flat / cR;
  float t = rois[j * 4 + 0], l = rois[j * 4 + 1];
  float bb = rois[j * 4 + 2], r = rois[j * 4 + 3];
  const u16* base = fmt + (size_t)n * (cH * cW) * cC;
  float gy = (py + 0.5f) / (float)cPP;
  float ys = fminf(fmaxf(t + gy * (bb - t), 0.0f), 63.0f);
  int y0 = (int)floorf(ys);
  int y1 = min(y0 + 1, 63);
  float wy = ys - (float)y0;
  #pragma unroll
  for (int px = 0; px < cPP; ++px) {
    float gx = (px + 0.5f) / (float)cPP;
    float xs = fminf(fmaxf(l + gx * (r - l), 0.0f), 63.0f);
    int x0 = (int)floorf(xs);
    int x1 = min(x0 + 1, 63);
    float wx = xs - (float)x0;
    float f00 = b2f(base[(y0 * cW + x0) * cC + c]);
    float f01 = b2f(base[(y0 * cW + x1) * cC + c]);
    float f10 = b2f(base[(y1 * cW + x0) * cC + c]);
    float f11 = b2f(base[(y1 * cW + x1) * cC + c]);
    float v = f00 * (1.0f - wy) * (1.0f - wx) + f01 * (1.0f - wy) * wx +
              f10 * wy * (1.0f - wx) + f11 * wy * wx;
    feat[((size_t)j * 49 + py * cPP + px) * cC + c] = f2b(v);
  }
}

// ================= K4: GEMM1 feat(256x12544 bf16) @ Wt(1024x12544 bf16)^T ===
// 1-D grid 1792, XCD-grouped decode: the 4 m-blocks sharing a (n,ksplit) Wt
// tile land on the same XCD (bid%8) adjacent in time -> Wt tile hits XCD L2.
// All loads k-contiguous dwordx4 (A: 2, B: 1 per thread per iter). LDS
// double-buffer, 16B-chunk XOR swizzle both sides, one barrier per swap.
// [Measured-best config: R2 = 184.6 total; R5's direct-A/raw-barrier variant
//  did NOT beat it (192.3). Reverting to the proven artifact.]
__global__ __launch_bounds__(256) void k_gemm1(const u16* __restrict__ feat, const u16* __restrict__ Wt,
                                               float* __restrict__ Cpart) {
  __shared__ u16 As[2][64][64];
  __shared__ u16 Bs[2][32][64];
  int tid = threadIdx.x;
  int bid = blockIdx.x;              // 0..1791
  int xcd = bid & 7, jj = bid >> 3;  // jj 0..223
  int gl = jj >> 2, m = jj & 3;      // gl 0..55
  int g = gl * 8 + xcd;              // 0..447 (bijective)
  int n0 = (g & 31) * 32;
  int ksp = g >> 5;                  // 0..13
  int kb0 = ksp * KCH;
  int m0 = m * 64;
  int lane = tid & 63, w = tid >> 6;
  int r = lane & 15, q = lane >> 4;
  f32x4 acc0 = {}, acc1 = {};

  // --- staging index math ---
  int am = tid >> 2;                  // A row 0..63
  int ac0 = (tid & 3) * 2;            // A chunk base 0,2,4,6
  int asw = am & 7;
  int ac0s = (ac0 ^ asw) * 8;
  int ac1s = ((ac0 + 1) ^ asw) * 8;
  int bn = tid >> 3, bc = tid & 7;    // B row 0..31, chunk 0..7
  int bcs = (bc ^ (bn & 7)) * 8;

  // --- fragment read offsets ---
  int rb = r & 7;
  int arow = w * 16 + r;
  int offK0 = (q ^ rb) * 8;           // ks=0 chunk q
  int offK1 = ((4 + q) ^ rb) * 8;     // ks=1 chunk 4+q

  const u16* ap = &feat[(size_t)(m0 + am) * cD + kb0 + ac0 * 8];
  const u16* bp = &Wt[(size_t)(n0 + bn) * cD + kb0 + bc * 8];

  uint4 a0A, a1A, bA, a0B, a1B, bB;
  a0A = *(const uint4*)ap; a1A = *(const uint4*)(ap + 8); bA = *(const uint4*)bp;
  ap += BK; bp += BK;
  a0B = *(const uint4*)ap; a1B = *(const uint4*)(ap + 8); bB = *(const uint4*)bp;
  ap += BK; bp += BK;
  *(uint4*)&As[0][am][ac0s] = a0A;
  *(uint4*)&As[0][am][ac1s] = a1A;
  *(uint4*)&Bs[0][bn][bcs] = bA;
  a0A = *(const uint4*)ap; a1A = *(const uint4*)(ap + 8); bA = *(const uint4*)bp;
  ap += BK; bp += BK;
  __syncthreads();

  #pragma unroll
  for (int it = 0; it < NITER; it += 2) {
    // even iter: store setB(it+1)->buf1, load it+3->setB, compute buf0
    *(uint4*)&As[1][am][ac0s] = a0B;
    *(uint4*)&As[1][am][ac1s] = a1B;
    *(uint4*)&Bs[1][bn][bcs] = bB;
    if (it + 3 < NITER) {
      a0B = *(const uint4*)ap; a1B = *(const uint4*)(ap + 8); bB = *(const uint4*)bp;
      ap += BK; bp += BK;
    }
    {
      short8 a0 = *(const short8*)&As[0][arow][offK0];
      short8 b00 = *(const short8*)&Bs[0][r][offK0];
      short8 b10 = *(const short8*)&Bs[0][16 + r][offK0];
      acc0 = __builtin_amdgcn_mfma_f32_16x16x32_bf16(a0, b00, acc0, 0, 0, 0);
      acc1 = __builtin_amdgcn_mfma_f32_16x16x32_bf16(a0, b10, acc1, 0, 0, 0);
      short8 a1 = *(const short8*)&As[0][arow][offK1];
      short8 b01 = *(const short8*)&Bs[0][r][offK1];
      short8 b11 = *(const short8*)&Bs[0][16 + r][offK1];
      acc0 = __builtin_amdgcn_mfma_f32_16x16x32_bf16(a1, b01, acc0, 0, 0, 0);
      acc1 = __builtin_amdgcn_mfma_f32_16x16x32_bf16(a1, b11, acc1, 0, 0, 0);
    }
    __syncthreads();
    // odd iter: store setA(it+2)->buf0, load it+4->setA, compute buf1
    if (it + 2 < NITER) {
      *(uint4*)&As[0][am][ac0s] = a0A;
      *(uint4*)&As[0][am][ac1s] = a1A;
      *(uint4*)&Bs[0][bn][bcs] = bA;
      if (it + 4 < NITER) {
        a0A = *(const uint4*)ap; a1A = *(const uint4*)(ap + 8); bA = *(const uint4*)bp;
        ap += BK; bp += BK;
      }
    }
    {
      short8 a0 = *(const short8*)&As[1][arow][offK0];
      short8 b00 = *(const short8*)&Bs[1][r][offK0];
      short8 b10 = *(const short8*)&Bs[1][16 + r][offK0];
      acc0 = __builtin_amdgcn_mfma_f32_16x16x32_bf16(a0, b00, acc0, 0, 0, 0);
      acc1 = __builtin_amdgcn_mfma_f32_16x16x32_bf16(a0, b10, acc1, 0, 0, 0);
      short8 a1 = *(const short8*)&As[1][arow][offK1];
      short8 b01 = *(const short8*)&Bs[1][r][offK1];
      short8 b11 = *(const short8*)&Bs[1][16 + r][offK1];
      acc0 = __builtin_amdgcn_mfma_f32_16x16x32_bf16(a1, b01, acc0, 0, 0, 0);
      acc1 = __builtin_amdgcn_mfma_f32_16x16x32_bf16(a1, b11, acc1, 0, 0, 0);
    }
    __syncthreads();
  }

  float* Cp = Cpart + (size_t)ksp * 256 * cDH;
  #pragma unroll
  for (int rg = 0; rg < 4; ++rg) {
    int row = m0 + w * 16 + q * 4 + rg;
    Cp[(size_t)row * cDH + n0 + r] = acc0[rg];
    Cp[(size_t)row * cDH + n0 + 16 + r] = acc1[rg];
  }
}

// ================= K5: heads + final losses (one block per roi row) =========
__global__ __launch_bounds__(256) void k_heads(
    const float* __restrict__ Cpart, const float* __restrict__ b1,
    const float* __restrict__ Wr, const float* __restrict__ br,
    const float* __restrict__ Wc, const float* __restrict__ bc,
    const int* __restrict__ cls_s, const float* __restrict__ tgt,
    float* __restrict__ out) {
  __shared__ float sacc[25];
  int row = blockIdx.x, tid = threadIdx.x, lane = tid & 63;
  if (tid < 25) sacc[tid] = 0.0f;
  __syncthreads();
  int k0 = tid * 4;
  float4 h = *(const float4*)&b1[k0];
  #pragma unroll
  for (int s = 0; s < SPLITS; ++s) {
    float4 c = *(const float4*)&Cpart[(size_t)s * 256 * cDH + (size_t)row * cDH + k0];
    h.x += c.x; h.y += c.y; h.z += c.z; h.w += c.w;
  }
  float hv[4] = {fmaxf(h.x, 0.f), fmaxf(h.y, 0.f), fmaxf(h.z, 0.f), fmaxf(h.w, 0.f)};
  float part[25];
  #pragma unroll
  for (int c = 0; c < 25; ++c) part[c] = 0.0f;
  #pragma unroll
  for (int j = 0; j < 4; ++j) {
    float4 wr = *(const float4*)&Wr[(k0 + j) * 4];
    part[0] += hv[j] * wr.x; part[1] += hv[j] * wr.y;
    part[2] += hv[j] * wr.z; part[3] += hv[j] * wr.w;
    const float* wc = &Wc[(k0 + j) * 21];
    #pragma unroll
    for (int c = 0; c < 21; ++c) part[4 + c] += hv[j] * wc[c];
  }
  #pragma unroll
  for (int off = 32; off; off >>= 1) {
    #pragma unroll
    for (int c = 0; c < 25; ++c) part[c] += __shfl_down(part[c], off, 64);
  }
  if (lane == 0) {
    #pragma unroll
    for (int c = 0; c < 25; ++c) atomicAdd(&sacc[c], part[c]);
  }
  __syncthreads();
  if (tid == 0) {
    int cls = cls_s[row];
    float m = -INFINITY;
    float vals[21];
    #pragma unroll
    for (int c = 0; c < 21; ++c) { vals[c] = sacc[4 + c] + bc[c]; m = fmaxf(m, vals[c]); }
    float sum = 0.0f;
    #pragma unroll
    for (int c = 0; c < 21; ++c) sum += expf(vals[c] - m);
    float lse = m + logf(sum);
    atomicAdd(&out[2], (lse - vals[cls]) * (1.0f / 256.0f));
    if (row < 64) {
      int am2 = 0; float bv = vals[0];
      #pragma unroll
      for (int c = 1; c < 21; ++c) if (vals[c] > bv) { bv = vals[c]; am2 = c; }
      if (am2 == cls) atomicAdd(&out[4], 1.0f / 64.0f);
    }
  }
  if (tid == 1 && row < 64) {
    float sl = 0.0f, of = 0.0f;
    #pragma unroll
    for (int c = 0; c < 4; ++c) {
      float d = fabsf((sacc[c] + br[c]) - tgt[row * 4 + c]);
      sl += (d < 1.0f) ? 0.5f * d * d : d - 0.5f;
      of += d;
    }
    atomicAdd(&out[3], sl * (1.0f / 256.0f));
    atomicAdd(&out[5], of * (1.0f / 256.0f));
  }
}

// ================= launch =================
extern "C" void kernel_launch(void* const* d_in, const int* in_sizes, int n_in,
                              void* d_out, int out_size, void* d_ws, size_t ws_size,
                              hipStream_t stream) {
  const float* nms_reg = (const float*)d_in[0];
  const float* fm      = (const float*)d_in[2];
  const float* bboxes  = (const float*)d_in[3];
  const int*   classes = (const int*)d_in[4];
  const float* anchors = (const float*)d_in[5];
  const float* rpn_reg = (const float*)d_in[6];
  const float* rpn_cls = (const float*)d_in[7];
  const float* W1      = (const float*)d_in[8];
  const float* b1      = (const float*)d_in[9];
  const float* Wr      = (const float*)d_in[10];
  const float* br      = (const float*)d_in[11];
  const float* Wc      = (const float*)d_in[12];
  const float* bc      = (const float*)d_in[13];
  float* out = (float*)d_out;
  char* ws = (char*)d_ws;

  int*      tidx  = (int*)(ws + O_TIDX);
  u64*      maskw = (u64*)(ws + O_MASKW);
  unsigned* keys  = (unsigned*)(ws + O_KEYS);
  int*      ridxg = (int*)(ws + O_RIDXG);
  int*      sel   = (int*)(ws + O_SEL);
  int*      clss  = (int*)(ws + O_CLS);
  float*    rois  = (float*)(ws + O_ROIS);
  float*    tgt   = (float*)(ws + O_TGT);
  u16*      fmt   = (u16*)(ws + O_FMT);
  u16*      feat  = (u16*)(ws + O_FEAT);
  float*    Cpart = (float*)(ws + O_CPART);
  u16*      wt    = (u16*)(ws + O_WT);

  k_front<<<608 + 1024 + 3136, 256, 0, stream>>>(bboxes, anchors, nms_reg, fm, W1,
                                                 tidx, maskw, keys, ridxg, fmt, wt);
  k_select<<<2, 1024, 0, stream>>>(maskw, tidx, rpn_cls, rpn_reg, bboxes, anchors,
                                   keys, ridxg, nms_reg, classes, sel, clss, rois, tgt, out);
  k_roi_pool<<<dim3(256, cPP), 256, 0, stream>>>(fmt, rois, sel, feat);
  k_gemm1<<<1792, 256, 0, stream>>>(feat, wt, Cpart);
  k_heads<<<256, 256, 0, stream>>>(Cpart, b1, Wr, br, Wc, bc, clss, tgt, out);
}